// Round 7
// baseline (94.650 us; speedup 1.0000x reference)
//
#include <hip/hip_runtime.h>
#include <hip/hip_bf16.h>
#include <stdint.h>

// Problem constants
#define BB 8
#define CC 64
#define NN 16384
#define KNB 8            // neighbors
// Padded GEMM1 K (REPERMUTED): cols kk*64+c = feature[c][idx[kk]] for kk=0..7,
// cols 512..519 = dis[0..7], cols 520..543 = 0.  (17 kb-steps of 32)

typedef __attribute__((ext_vector_type(8))) short   s16x8;
typedef __attribute__((ext_vector_type(4))) short   s16x4;
typedef __attribute__((ext_vector_type(8))) __bf16  bf16x8;
typedef __attribute__((ext_vector_type(4))) float   f32x4;

__device__ __forceinline__ unsigned short f2bf(float f) {
    unsigned u = __builtin_bit_cast(unsigned, f);
    u = (u + 0x7FFFu + ((u >> 16) & 1u)) >> 16;   // RNE, inputs finite
    return (unsigned short)u;
}

__device__ __forceinline__ int getq(const int4& q, int j) {
    return j == 0 ? q.x : j == 1 ? q.y : j == 2 ? q.z : q.w;   // j constant-folds after unroll
}

// ---- workspace layout (bytes) ----
#define OFF_DISB  16777216u
#define OFF_W1B   18874368u
#define OFF_W2B   19013632u
#define OFF_W3B   19046400u

// ---------------- prep: dis->bf16, weights->bf16 fragment-major ----------------
__global__ __launch_bounds__(256) void prep_misc(
    const float* __restrict__ dis, const float* __restrict__ W1,
    const float* __restrict__ W2, const float* __restrict__ W3,
    unsigned short* __restrict__ disB, unsigned short* __restrict__ w1p,
    unsigned short* __restrict__ w2p, unsigned short* __restrict__ w3p)
{
    int tid = blockIdx.x * 256 + threadIdx.x;
    if (tid < 131072) {                        // one POINT per thread: 8 dis values
        const float* dp = dis + (size_t)tid * 8;
        s16x8 pk;
        #pragma unroll
        for (int j = 0; j < 8; ++j) pk[j] = (short)f2bf(dp[j]);
        *(s16x8*)(disB + (size_t)tid * 8) = pk;
        return;
    }
    int t2 = tid - 131072;
    if (t2 < 8704) {                           // W1p: kb 0..16, t 0..7, lane 0..63
        int kb   = t2 >> 9;
        int rem  = t2 & 511;
        int t    = rem >> 6;
        int lane = rem & 63;
        int row  = t * 16 + (lane & 15);
        int kbase = kb * 32 + (lane >> 4) * 8;
        s16x8 pk;
        #pragma unroll
        for (int j = 0; j < 8; ++j) {
            int kp = kbase + j;
            float val = 0.f;
            if (kp < 512) {                                          // feature weights
                int kk = kp >> 6, c = kp & 63;
                val = W1[row * 520 + kk * 65 + 1 + c];
            } else if (kp < 520) {                                   // dis weight of neighbor kp-512
                val = W1[row * 520 + (kp - 512) * 65];
            }
            pk[j] = (short)f2bf(val);
        }
        *(s16x8*)(w1p + (size_t)t2 * 8) = pk;
    } else if (t2 < 8704 + 2048) {             // W2p
        int f    = t2 - 8704;
        int kb   = f >> 9;
        int rem  = f & 511;
        int t    = rem >> 6;
        int lane = rem & 63;
        int row  = t * 16 + (lane & 15);
        int k    = kb * 32 + (lane >> 4) * 8;
        s16x8 pk;
        #pragma unroll
        for (int j = 0; j < 8; ++j) pk[j] = (short)f2bf(W2[row * 128 + k + j]);
        *(s16x8*)(w2p + (size_t)f * 8) = pk;
    } else if (t2 < 8704 + 2048 + 4096) {      // W3p
        int f    = t2 - 10752;
        int hk   = f >> 9;
        int half = hk >> 2, kb = hk & 3;
        int rem  = f & 511;
        int t    = rem >> 6;
        int lane = rem & 63;
        int row  = (half * 8 + t) * 16 + (lane & 15);
        int k    = kb * 32 + (lane >> 4) * 8;
        s16x8 pk;
        #pragma unroll
        for (int j = 0; j < 8; ++j) pk[j] = (short)f2bf(W3[row * 128 + k + j]);
        *(s16x8*)(w3p + (size_t)f * 8) = pk;
    }
}

// ---------------- prep: feature [B][C][N] fp32 -> featT [B][N][C] bf16 ----------------
__global__ __launch_bounds__(256) void prep_featT(
    const float* __restrict__ feat, unsigned short* __restrict__ featT)
{
    int gt = blockIdx.x * 256 + threadIdx.x;
    int b = gt >> 14, n = gt & 16383;
    const float* fp = feat + ((size_t)b << 20) + n;
    unsigned short v[64];
    #pragma unroll
    for (int c = 0; c < 64; ++c) v[c] = f2bf(fp[(size_t)c << 14]);
    unsigned short* dst = featT + (size_t)gt * 64;
    #pragma unroll
    for (int j = 0; j < 8; ++j) {
        s16x8 pk;
        #pragma unroll
        for (int i = 0; i < 8; ++i) pk[i] = (short)v[j * 8 + i];
        *(s16x8*)(dst + j * 8) = pk;
    }
}

// ---------------- main fused kernel helpers ----------------
__device__ __forceinline__ void wload4(const unsigned short* wp, int frag0, int lane,
                                       bf16x8& w0, bf16x8& w1, bf16x8& w2, bf16x8& w3)
{
    w0 = *(const bf16x8*)(wp + (size_t)((frag0 + 0) * 64 + lane) * 8);
    w1 = *(const bf16x8*)(wp + (size_t)((frag0 + 1) * 64 + lane) * 8);
    w2 = *(const bf16x8*)(wp + (size_t)((frag0 + 2) * 64 + lane) * 8);
    w3 = *(const bf16x8*)(wp + (size_t)((frag0 + 3) * 64 + lane) * 8);
}

template <int KB>
__device__ __forceinline__ void gather2(const unsigned short* featB, const int4 (&iq)[2][2],
                                        int grp8, bf16x8& G0, bf16x8& G1)
{
    constexpr int kk = KB >> 1;
    const int c0 = (KB & 1) * 32 + grp8;
    G0 = *(const bf16x8*)(featB + (((size_t)(unsigned)getq(iq[0][kk >> 2], kk & 3)) << 6) + c0);
    G1 = *(const bf16x8*)(featB + (((size_t)(unsigned)getq(iq[1][kk >> 2], kk & 3)) << 6) + c0);
}

// dis columns (kb=16 data): grp 0 lanes carry dis[0..7], other grps are zero pad
__device__ __forceinline__ void disload2(const unsigned short* disB, int p0, int l15, int grp,
                                         bf16x8& G0, bf16x8& G1)
{
    const s16x8 z = {0,0,0,0,0,0,0,0};
    if (grp == 0) {
        G0 = *(const bf16x8*)(disB + (size_t)(p0 +  0 + l15) * 8);
        G1 = *(const bf16x8*)(disB + (size_t)(p0 + 16 + l15) * 8);
    } else {
        G0 = __builtin_bit_cast(bf16x8, z); G1 = __builtin_bit_cast(bf16x8, z);
    }
}

__device__ __forceinline__ void dsread2(const unsigned short* strip, int kb, int l15, int grp8,
                                        bf16x8& G0, bf16x8& G1)
{
    G0 = *(const bf16x8*)(strip + (0 * 16 + l15) * 136 + kb * 32 + grp8);
    G1 = *(const bf16x8*)(strip + (1 * 16 + l15) * 136 + kb * 32 + grp8);
}

// 4 weight frags x 2 point-tiles = 8 MFMAs
__device__ __forceinline__ void mfma_oct(f32x4 (&ac)[8][2], int t0,
    const bf16x8& wa, const bf16x8& wb, const bf16x8& wc, const bf16x8& wd,
    const bf16x8& B0, const bf16x8& B1)
{
    ac[t0+0][0] = __builtin_amdgcn_mfma_f32_16x16x32_bf16(wa, B0, ac[t0+0][0], 0, 0, 0);
    ac[t0+0][1] = __builtin_amdgcn_mfma_f32_16x16x32_bf16(wa, B1, ac[t0+0][1], 0, 0, 0);
    ac[t0+1][0] = __builtin_amdgcn_mfma_f32_16x16x32_bf16(wb, B0, ac[t0+1][0], 0, 0, 0);
    ac[t0+1][1] = __builtin_amdgcn_mfma_f32_16x16x32_bf16(wb, B1, ac[t0+1][1], 0, 0, 0);
    ac[t0+2][0] = __builtin_amdgcn_mfma_f32_16x16x32_bf16(wc, B0, ac[t0+2][0], 0, 0, 0);
    ac[t0+2][1] = __builtin_amdgcn_mfma_f32_16x16x32_bf16(wc, B1, ac[t0+2][1], 0, 0, 0);
    ac[t0+3][0] = __builtin_amdgcn_mfma_f32_16x16x32_bf16(wd, B0, ac[t0+3][0], 0, 0, 0);
    ac[t0+3][1] = __builtin_amdgcn_mfma_f32_16x16x32_bf16(wd, B1, ac[t0+3][1], 0, 0, 0);
}

// ---------------- main fused kernel ----------------
// 1 wave per block, 32 points per wave (2 pt-tiles): higher occupancy (3 waves/SIMD)
// for latency hiding; software-pipelined loads as before. Zero barriers.
__global__ __launch_bounds__(64, 3) void pointconv_main(
    const unsigned short* __restrict__ featT,
    const unsigned short* __restrict__ disB,
    const int* __restrict__ idx,
    const unsigned short* __restrict__ w1p,
    const unsigned short* __restrict__ w2p,
    const unsigned short* __restrict__ w3p,
    const float* __restrict__ b1, const float* __restrict__ b2,
    const float* __restrict__ b3, float* __restrict__ out)
{
    __shared__ __align__(16) unsigned short strip[32 * 136];   // 8,704 B
    const int bid  = blockIdx.x;
    const int wg   = (bid & 7) * 512 + (bid >> 3);     // XCD-aware bijective swizzle (4096 blocks)
    const int lane = threadIdx.x;                      // 0..63
    const int grp  = lane >> 4;
    const int grp8 = grp * 8;
    const int l15  = lane & 15;
    const int p0   = wg * 32;
    const int b    = p0 >> 14;
    const int n0   = p0 & 16383;

    // pipeline registers
    bf16x8 gA0, gA1, gB0, gB1;                         // B-frag double buffer
    bf16x8 wA0, wA1, wA2, wA3, wB0, wB1, wB2, wB3;     // weight quad double buffer

    // ---- prolog: first weights, idx, first two gather sets ----
    wload4(w1p, 0, lane, wA0, wA1, wA2, wA3);

    int4 idxq[2][2];
    #pragma unroll
    for (int pt = 0; pt < 2; ++pt) {
        const int* ip = idx + (size_t)(p0 + pt * 16 + l15) * 8;
        idxq[pt][0] = *(const int4*)ip;
        idxq[pt][1] = *(const int4*)(ip + 4);
    }
    const unsigned short* featB = featT + ((size_t)b << 20);

    gather2<0>(featB, idxq, grp8, gA0, gA1);
    gather2<1>(featB, idxq, grp8, gB0, gB1);

    // ================= GEMM1: [128 x 544] * [544 x 32] =================
    f32x4 acc[8][2];
    #pragma unroll
    for (int t = 0; t < 8; ++t)
        #pragma unroll
        for (int pt = 0; pt < 2; ++pt) acc[t][pt] = (f32x4){0.f, 0.f, 0.f, 0.f};

#define G1_BODY(KB, S0,S1, WNEXT, GNEXT)                                    \
    wload4(w1p, (KB)*8 + 4, lane, wB0, wB1, wB2, wB3);                      \
    mfma_oct(acc, 0, wA0, wA1, wA2, wA3, S0, S1);                           \
    WNEXT;                                                                  \
    mfma_oct(acc, 4, wB0, wB1, wB2, wB3, S0, S1);                           \
    GNEXT;

    G1_BODY(0,  gA0,gA1, wload4(w1p,  8, lane, wA0,wA1,wA2,wA3), (gather2< 2>(featB, idxq, grp8, gA0,gA1)))
    G1_BODY(1,  gB0,gB1, wload4(w1p, 16, lane, wA0,wA1,wA2,wA3), (gather2< 3>(featB, idxq, grp8, gB0,gB1)))
    G1_BODY(2,  gA0,gA1, wload4(w1p, 24, lane, wA0,wA1,wA2,wA3), (gather2< 4>(featB, idxq, grp8, gA0,gA1)))
    G1_BODY(3,  gB0,gB1, wload4(w1p, 32, lane, wA0,wA1,wA2,wA3), (gather2< 5>(featB, idxq, grp8, gB0,gB1)))
    G1_BODY(4,  gA0,gA1, wload4(w1p, 40, lane, wA0,wA1,wA2,wA3), (gather2< 6>(featB, idxq, grp8, gA0,gA1)))
    G1_BODY(5,  gB0,gB1, wload4(w1p, 48, lane, wA0,wA1,wA2,wA3), (gather2< 7>(featB, idxq, grp8, gB0,gB1)))
    G1_BODY(6,  gA0,gA1, wload4(w1p, 56, lane, wA0,wA1,wA2,wA3), (gather2< 8>(featB, idxq, grp8, gA0,gA1)))
    G1_BODY(7,  gB0,gB1, wload4(w1p, 64, lane, wA0,wA1,wA2,wA3), (gather2< 9>(featB, idxq, grp8, gB0,gB1)))
    G1_BODY(8,  gA0,gA1, wload4(w1p, 72, lane, wA0,wA1,wA2,wA3), (gather2<10>(featB, idxq, grp8, gA0,gA1)))
    G1_BODY(9,  gB0,gB1, wload4(w1p, 80, lane, wA0,wA1,wA2,wA3), (gather2<11>(featB, idxq, grp8, gB0,gB1)))
    G1_BODY(10, gA0,gA1, wload4(w1p, 88, lane, wA0,wA1,wA2,wA3), (gather2<12>(featB, idxq, grp8, gA0,gA1)))
    G1_BODY(11, gB0,gB1, wload4(w1p, 96, lane, wA0,wA1,wA2,wA3), (gather2<13>(featB, idxq, grp8, gB0,gB1)))
    G1_BODY(12, gA0,gA1, wload4(w1p,104, lane, wA0,wA1,wA2,wA3), (gather2<14>(featB, idxq, grp8, gA0,gA1)))
    G1_BODY(13, gB0,gB1, wload4(w1p,112, lane, wA0,wA1,wA2,wA3), (gather2<15>(featB, idxq, grp8, gB0,gB1)))
    // kb=14: "next gather" slot loads the dis columns (kb=16 data) into the gA set
    G1_BODY(14, gA0,gA1, wload4(w1p,120, lane, wA0,wA1,wA2,wA3), disload2(disB, p0, l15, grp, gA0,gA1))
    G1_BODY(15, gB0,gB1, wload4(w1p,128, lane, wA0,wA1,wA2,wA3), )
    // kb=16 (dis/zero cols); next-weight prefetch chains into GEMM2's first quad
    G1_BODY(16, gA0,gA1, wload4(w2p, 0, lane, wA0,wA1,wA2,wA3), )
#undef G1_BODY

    // epilogue 1: bias + relu -> strip[pt][ch] bf16
    #pragma unroll
    for (int t = 0; t < 8; ++t) {
        const int chb = t * 16 + grp * 4;
        const float4 bv = *(const float4*)(b1 + chb);
        #pragma unroll
        for (int pt = 0; pt < 2; ++pt) {
            s16x4 pk;
            float v0 = acc[t][pt][0] + bv.x; pk[0] = (short)f2bf(v0 > 0.f ? v0 : 0.f);
            float v1 = acc[t][pt][1] + bv.y; pk[1] = (short)f2bf(v1 > 0.f ? v1 : 0.f);
            float v2 = acc[t][pt][2] + bv.z; pk[2] = (short)f2bf(v2 > 0.f ? v2 : 0.f);
            float v3 = acc[t][pt][3] + bv.w; pk[3] = (short)f2bf(v3 > 0.f ? v3 : 0.f);
            *(s16x4*)(strip + (pt * 16 + l15) * 136 + chb) = pk;
        }
    }

    // ================= GEMM2: [128 x 128] * [128 x 32] =================
    f32x4 acc2[8][2];
    #pragma unroll
    for (int t = 0; t < 8; ++t)
        #pragma unroll
        for (int pt = 0; pt < 2; ++pt) acc2[t][pt] = (f32x4){0.f, 0.f, 0.f, 0.f};

    dsread2(strip, 0, l15, grp8, gA0, gA1);

#define G23_BODY(WP, FR, S0,S1, ACC, WNEXT, DSNEXT)                         \
    wload4(WP, (FR) + 4, lane, wB0, wB1, wB2, wB3);                         \
    mfma_oct(ACC, 0, wA0, wA1, wA2, wA3, S0, S1);                           \
    WNEXT;                                                                  \
    DSNEXT;                                                                 \
    mfma_oct(ACC, 4, wB0, wB1, wB2, wB3, S0, S1);

    G23_BODY(w2p,  0, gA0,gA1, acc2, wload4(w2p,  8, lane, wA0,wA1,wA2,wA3), dsread2(strip, 1, l15, grp8, gB0,gB1))
    G23_BODY(w2p,  8, gB0,gB1, acc2, wload4(w2p, 16, lane, wA0,wA1,wA2,wA3), dsread2(strip, 2, l15, grp8, gA0,gA1))
    G23_BODY(w2p, 16, gA0,gA1, acc2, wload4(w2p, 24, lane, wA0,wA1,wA2,wA3), dsread2(strip, 3, l15, grp8, gB0,gB1))
    G23_BODY(w2p, 24, gB0,gB1, acc2, wload4(w3p,  0, lane, wA0,wA1,wA2,wA3), )

    // epilogue 2: bias + relu -> strip (H1 fully consumed; same-wave ordering)
    #pragma unroll
    for (int t = 0; t < 8; ++t) {
        const int chb = t * 16 + grp * 4;
        const float4 bv = *(const float4*)(b2 + chb);
        #pragma unroll
        for (int pt = 0; pt < 2; ++pt) {
            s16x4 pk;
            float v0 = acc2[t][pt][0] + bv.x; pk[0] = (short)f2bf(v0 > 0.f ? v0 : 0.f);
            float v1 = acc2[t][pt][1] + bv.y; pk[1] = (short)f2bf(v1 > 0.f ? v1 : 0.f);
            float v2 = acc2[t][pt][2] + bv.z; pk[2] = (short)f2bf(v2 > 0.f ? v2 : 0.f);
            float v3 = acc2[t][pt][3] + bv.w; pk[3] = (short)f2bf(v3 > 0.f ? v3 : 0.f);
            *(s16x4*)(strip + (pt * 16 + l15) * 136 + chb) = pk;
        }
    }

    // ================= GEMM3: [256 x 128] * [128 x 32], two halves =================
    #pragma unroll
    for (int half = 0; half < 2; ++half) {
        f32x4 acc3[8][2];
        #pragma unroll
        for (int t = 0; t < 8; ++t)
            #pragma unroll
            for (int pt = 0; pt < 2; ++pt) acc3[t][pt] = (f32x4){0.f, 0.f, 0.f, 0.f};

        dsread2(strip, 0, l15, grp8, gA0, gA1);
        if (half == 0) {
            G23_BODY(w3p,  0, gA0,gA1, acc3, wload4(w3p,  8, lane, wA0,wA1,wA2,wA3), dsread2(strip, 1, l15, grp8, gB0,gB1))
            G23_BODY(w3p,  8, gB0,gB1, acc3, wload4(w3p, 16, lane, wA0,wA1,wA2,wA3), dsread2(strip, 2, l15, grp8, gA0,gA1))
            G23_BODY(w3p, 16, gA0,gA1, acc3, wload4(w3p, 24, lane, wA0,wA1,wA2,wA3), dsread2(strip, 3, l15, grp8, gB0,gB1))
            G23_BODY(w3p, 24, gB0,gB1, acc3, wload4(w3p, 32, lane, wA0,wA1,wA2,wA3), )
        } else {
            G23_BODY(w3p, 32, gA0,gA1, acc3, wload4(w3p, 40, lane, wA0,wA1,wA2,wA3), dsread2(strip, 1, l15, grp8, gB0,gB1))
            G23_BODY(w3p, 40, gB0,gB1, acc3, wload4(w3p, 48, lane, wA0,wA1,wA2,wA3), dsread2(strip, 2, l15, grp8, gA0,gA1))
            G23_BODY(w3p, 48, gA0,gA1, acc3, wload4(w3p, 56, lane, wA0,wA1,wA2,wA3), dsread2(strip, 3, l15, grp8, gB0,gB1))
            G23_BODY(w3p, 56, gB0,gB1, acc3, , )
        }

        #pragma unroll
        for (int t = 0; t < 8; ++t) {
            const int chb = half * 128 + t * 16 + grp * 4;
            const float4 bv = *(const float4*)(b3 + chb);
            #pragma unroll
            for (int pt = 0; pt < 2; ++pt) {
                const int n = n0 + pt * 16 + l15;
                float* op = out + (((size_t)(b * 256 + chb)) << 14) + n;
                op[0]                  = acc3[t][pt][0] + bv.x;
                op[(size_t)1 << 14]    = acc3[t][pt][1] + bv.y;
                op[(size_t)2 << 14]    = acc3[t][pt][2] + bv.z;
                op[(size_t)3 << 14]    = acc3[t][pt][3] + bv.w;
            }
        }
    }
#undef G23_BODY
}

extern "C" void kernel_launch(void* const* d_in, const int* in_sizes, int n_in,
                              void* d_out, int out_size, void* d_ws, size_t ws_size,
                              hipStream_t stream)
{
    const float* feature = (const float*)d_in[0];
    const int*   idx     = (const int*)d_in[1];
    const float* dis     = (const float*)d_in[2];
    const float* W1      = (const float*)d_in[3];
    const float* b1      = (const float*)d_in[4];
    const float* W2      = (const float*)d_in[5];
    const float* b2      = (const float*)d_in[6];
    const float* W3      = (const float*)d_in[7];
    const float* b3      = (const float*)d_in[8];
    float* out = (float*)d_out;

    char* ws = (char*)d_ws;
    unsigned short* featT = (unsigned short*)ws;
    unsigned short* disB  = (unsigned short*)(ws + OFF_DISB);
    unsigned short* w1p   = (unsigned short*)(ws + OFF_W1B);
    unsigned short* w2p   = (unsigned short*)(ws + OFF_W2B);
    unsigned short* w3p   = (unsigned short*)(ws + OFF_W3B);

    hipLaunchKernelGGL(prep_misc, dim3(570), dim3(256), 0, stream,
                       dis, W1, W2, W3, disB, w1p, w2p, w3p);
    hipLaunchKernelGGL(prep_featT, dim3(512), dim3(256), 0, stream, feature, featT);
    hipLaunchKernelGGL(pointconv_main, dim3(4096), dim3(64), 0, stream,
                       featT, disB, idx, w1p, w2p, w3p, b1, b2, b3, out);
}

// Round 8
// 87.253 us; speedup vs baseline: 1.0848x; 1.0848x over previous
//
#include <hip/hip_runtime.h>
#include <hip/hip_bf16.h>
#include <stdint.h>

// Problem constants
#define BB 8
#define CC 64
#define NN 16384
#define KNB 8            // neighbors
// Padded GEMM1 K (REPERMUTED): cols kk*64+c = feature[c][idx[kk]] for kk=0..7,
// cols 512..519 = dis[0..7], cols 520..543 = 0.  (17 kb-steps of 32)

typedef __attribute__((ext_vector_type(8))) short   s16x8;
typedef __attribute__((ext_vector_type(4))) short   s16x4;
typedef __attribute__((ext_vector_type(8))) __bf16  bf16x8;
typedef __attribute__((ext_vector_type(4))) float   f32x4;

typedef const __attribute__((address_space(1))) unsigned int gas_u32;
typedef __attribute__((address_space(3))) unsigned int       las_u32;

__device__ __forceinline__ unsigned short f2bf(float f) {
    unsigned u = __builtin_bit_cast(unsigned, f);
    u = (u + 0x7FFFu + ((u >> 16) & 1u)) >> 16;   // RNE, inputs finite
    return (unsigned short)u;
}

__device__ __forceinline__ int getq(const int4& q, int j) {
    return j == 0 ? q.x : j == 1 ? q.y : j == 2 ? q.z : q.w;   // j constant-folds after unroll
}

// ---- workspace layout (bytes) ----
#define OFF_DISB  16777216u
#define OFF_W1B   18874368u
#define OFF_W2B   19013632u
#define OFF_W3B   19046400u

// ---------------- prep: dis->bf16, weights->bf16 fragment-major ----------------
__global__ __launch_bounds__(256) void prep_misc(
    const float* __restrict__ dis, const float* __restrict__ W1,
    const float* __restrict__ W2, const float* __restrict__ W3,
    unsigned short* __restrict__ disB, unsigned short* __restrict__ w1p,
    unsigned short* __restrict__ w2p, unsigned short* __restrict__ w3p)
{
    int tid = blockIdx.x * 256 + threadIdx.x;
    if (tid < 131072) {                        // one POINT per thread: 8 dis values
        const float* dp = dis + (size_t)tid * 8;
        s16x8 pk;
        #pragma unroll
        for (int j = 0; j < 8; ++j) pk[j] = (short)f2bf(dp[j]);
        *(s16x8*)(disB + (size_t)tid * 8) = pk;
        return;
    }
    int t2 = tid - 131072;
    if (t2 < 8704) {                           // W1p: kb 0..16, t 0..7, lane 0..63
        int kb   = t2 >> 9;
        int rem  = t2 & 511;
        int t    = rem >> 6;
        int lane = rem & 63;
        int row  = t * 16 + (lane & 15);
        int kbase = kb * 32 + (lane >> 4) * 8;
        s16x8 pk;
        #pragma unroll
        for (int j = 0; j < 8; ++j) {
            int kp = kbase + j;
            float val = 0.f;
            if (kp < 512) {                                          // feature weights
                int kk = kp >> 6, c = kp & 63;
                val = W1[row * 520 + kk * 65 + 1 + c];
            } else if (kp < 520) {                                   // dis weight of neighbor kp-512
                val = W1[row * 520 + (kp - 512) * 65];
            }
            pk[j] = (short)f2bf(val);
        }
        *(s16x8*)(w1p + (size_t)t2 * 8) = pk;
    } else if (t2 < 8704 + 2048) {             // W2p
        int f    = t2 - 8704;
        int kb   = f >> 9;
        int rem  = f & 511;
        int t    = rem >> 6;
        int lane = rem & 63;
        int row  = t * 16 + (lane & 15);
        int k    = kb * 32 + (lane >> 4) * 8;
        s16x8 pk;
        #pragma unroll
        for (int j = 0; j < 8; ++j) pk[j] = (short)f2bf(W2[row * 128 + k + j]);
        *(s16x8*)(w2p + (size_t)f * 8) = pk;
    } else if (t2 < 8704 + 2048 + 4096) {      // W3p
        int f    = t2 - 10752;
        int hk   = f >> 9;
        int half = hk >> 2, kb = hk & 3;
        int rem  = f & 511;
        int t    = rem >> 6;
        int lane = rem & 63;
        int row  = (half * 8 + t) * 16 + (lane & 15);
        int k    = kb * 32 + (lane >> 4) * 8;
        s16x8 pk;
        #pragma unroll
        for (int j = 0; j < 8; ++j) pk[j] = (short)f2bf(W3[row * 128 + k + j]);
        *(s16x8*)(w3p + (size_t)f * 8) = pk;
    }
}

// ---------------- prep: feature [B][C][N] fp32 -> featT [B][N][C] bf16 ----------------
__global__ __launch_bounds__(256) void prep_featT(
    const float* __restrict__ feat, unsigned short* __restrict__ featT)
{
    int gt = blockIdx.x * 256 + threadIdx.x;
    int b = gt >> 14, n = gt & 16383;
    const float* fp = feat + ((size_t)b << 20) + n;
    unsigned short v[64];
    #pragma unroll
    for (int c = 0; c < 64; ++c) v[c] = f2bf(fp[(size_t)c << 14]);
    unsigned short* dst = featT + (size_t)gt * 64;
    #pragma unroll
    for (int j = 0; j < 8; ++j) {
        s16x8 pk;
        #pragma unroll
        for (int i = 0; i < 8; ++i) pk[i] = (short)v[j * 8 + i];
        *(s16x8*)(dst + j * 8) = pk;
    }
}

// ---------------- main fused kernel helpers ----------------
// stage one 8KB weight chunk (8 frags) into an LDS slot, 256 threads x 2 x 16B
__device__ __forceinline__ void stage_chunk(const unsigned short* wsrc, unsigned short* dst, int tid)
{
    const char* g = (const char*)wsrc + (size_t)tid * 16;
    char*       l = (char*)dst        + (size_t)tid * 16;
    __builtin_amdgcn_global_load_lds((gas_u32*)g,          (las_u32*)l,          16, 0, 0);
    __builtin_amdgcn_global_load_lds((gas_u32*)(g + 4096), (las_u32*)(l + 4096), 16, 0, 0);
}

// compute one 8-frag chunk from LDS slot against 2 point-tiles (16 MFMAs)
__device__ __forceinline__ void mfma_chunk(f32x4 (&ac)[8][2], const unsigned short* slot, int lane,
                                           const bf16x8& B0, const bf16x8& B1)
{
    #pragma unroll
    for (int j = 0; j < 8; ++j) {
        bf16x8 w = *(const bf16x8*)(slot + (size_t)((j * 64 + lane) * 8));
        ac[j][0] = __builtin_amdgcn_mfma_f32_16x16x32_bf16(w, B0, ac[j][0], 0, 0, 0);
        ac[j][1] = __builtin_amdgcn_mfma_f32_16x16x32_bf16(w, B1, ac[j][1], 0, 0, 0);
    }
}

__device__ __forceinline__ void wload4(const unsigned short* wp, int frag0, int lane,
                                       bf16x8& w0, bf16x8& w1, bf16x8& w2, bf16x8& w3)
{
    w0 = *(const bf16x8*)(wp + (size_t)((frag0 + 0) * 64 + lane) * 8);
    w1 = *(const bf16x8*)(wp + (size_t)((frag0 + 1) * 64 + lane) * 8);
    w2 = *(const bf16x8*)(wp + (size_t)((frag0 + 2) * 64 + lane) * 8);
    w3 = *(const bf16x8*)(wp + (size_t)((frag0 + 3) * 64 + lane) * 8);
}

template <int KB>
__device__ __forceinline__ void gather2(const unsigned short* featB, const int4 (&iq)[2][2],
                                        int grp8, bf16x8& G0, bf16x8& G1)
{
    constexpr int kk = KB >> 1;
    const int c0 = (KB & 1) * 32 + grp8;
    G0 = *(const bf16x8*)(featB + (((size_t)(unsigned)getq(iq[0][kk >> 2], kk & 3)) << 6) + c0);
    G1 = *(const bf16x8*)(featB + (((size_t)(unsigned)getq(iq[1][kk >> 2], kk & 3)) << 6) + c0);
}

// dis columns (kb=16 data): grp 0 lanes carry dis[0..7], other grps are zero pad
__device__ __forceinline__ void disload2(const unsigned short* disB, int p0, int l15, int grp,
                                         bf16x8& G0, bf16x8& G1)
{
    const s16x8 z = {0,0,0,0,0,0,0,0};
    if (grp == 0) {
        G0 = *(const bf16x8*)(disB + (size_t)(p0 +  0 + l15) * 8);
        G1 = *(const bf16x8*)(disB + (size_t)(p0 + 16 + l15) * 8);
    } else {
        G0 = __builtin_bit_cast(bf16x8, z); G1 = __builtin_bit_cast(bf16x8, z);
    }
}

__device__ __forceinline__ void dsread2(const unsigned short* strip, int kb, int l15, int grp8,
                                        bf16x8& G0, bf16x8& G1)
{
    G0 = *(const bf16x8*)(strip + (0 * 16 + l15) * 136 + kb * 32 + grp8);
    G1 = *(const bf16x8*)(strip + (1 * 16 + l15) * 136 + kb * 32 + grp8);
}

// 4 weight frags x 2 point-tiles = 8 MFMAs (register-weight path, used by GEMM3)
__device__ __forceinline__ void mfma_oct(f32x4 (&ac)[8][2], int t0,
    const bf16x8& wa, const bf16x8& wb, const bf16x8& wc, const bf16x8& wd,
    const bf16x8& B0, const bf16x8& B1)
{
    ac[t0+0][0] = __builtin_amdgcn_mfma_f32_16x16x32_bf16(wa, B0, ac[t0+0][0], 0, 0, 0);
    ac[t0+0][1] = __builtin_amdgcn_mfma_f32_16x16x32_bf16(wa, B1, ac[t0+0][1], 0, 0, 0);
    ac[t0+1][0] = __builtin_amdgcn_mfma_f32_16x16x32_bf16(wb, B0, ac[t0+1][0], 0, 0, 0);
    ac[t0+1][1] = __builtin_amdgcn_mfma_f32_16x16x32_bf16(wb, B1, ac[t0+1][1], 0, 0, 0);
    ac[t0+2][0] = __builtin_amdgcn_mfma_f32_16x16x32_bf16(wc, B0, ac[t0+2][0], 0, 0, 0);
    ac[t0+2][1] = __builtin_amdgcn_mfma_f32_16x16x32_bf16(wc, B1, ac[t0+2][1], 0, 0, 0);
    ac[t0+3][0] = __builtin_amdgcn_mfma_f32_16x16x32_bf16(wd, B0, ac[t0+3][0], 0, 0, 0);
    ac[t0+3][1] = __builtin_amdgcn_mfma_f32_16x16x32_bf16(wd, B1, ac[t0+3][1], 0, 0, 0);
}

// ---------------- main fused kernel ----------------
// 4 waves (256 thr) per block, 32 pts/wave = 128 pts/block, 1024 blocks.
// GEMM1+GEMM2 weights staged into LDS (8KB chunks, double-buffered, 1 barrier/chunk),
// shared by all 4 waves -> 4x less weight fetch, LDS latency instead of L2.
// GEMM3 weights register-pipelined from global; NO barriers after GEMM2 so the
// 134MB store stream is never drained mid-kernel. H1/H2 in per-wave LDS strips.
__global__ __launch_bounds__(256, 3) void pointconv_main(
    const unsigned short* __restrict__ featT,
    const unsigned short* __restrict__ disB,
    const int* __restrict__ idx,
    const unsigned short* __restrict__ w1p,
    const unsigned short* __restrict__ w2p,
    const unsigned short* __restrict__ w3p,
    const float* __restrict__ b1, const float* __restrict__ b2,
    const float* __restrict__ b3, float* __restrict__ out)
{
    __shared__ __align__(16) unsigned short ldsw[2 * 4096];    // two 8KB weight slots
    __shared__ __align__(16) unsigned short ldsh[4 * 4352];    // 4 per-wave H strips (32x136)
    const int bid  = blockIdx.x;
    const int wg   = (bid & 7) * 128 + (bid >> 3);     // XCD swizzle: 1024 blocks, 128/XCD = 1 batch
    const int tid  = threadIdx.x;
    const int wv   = tid >> 6;
    const int lane = tid & 63;
    const int grp  = lane >> 4;
    const int grp8 = grp * 8;
    const int l15  = lane & 15;
    const int p0   = wg * 128 + wv * 32;               // this wave's first point
    const int b    = p0 >> 14;
    const int n0   = p0 & 16383;

    unsigned short* wb0   = ldsw;
    unsigned short* wb1   = ldsw + 4096;
    unsigned short* strip = ldsh + wv * 4352;

    bf16x8 gA0, gA1, gB0, gB1;                         // B-frag double buffer
    bf16x8 wA0, wA1, wA2, wA3, wB0, wB1, wB2, wB3;     // GEMM3 weight quads

    // ---- prolog: stage chunk 0; idx + first two gather sets ----
    stage_chunk(w1p, wb0, tid);

    int4 idxq[2][2];
    #pragma unroll
    for (int pt = 0; pt < 2; ++pt) {
        const int* ip = idx + (size_t)(p0 + pt * 16 + l15) * 8;
        idxq[pt][0] = *(const int4*)ip;
        idxq[pt][1] = *(const int4*)(ip + 4);
    }
    const unsigned short* featB = featT + ((size_t)b << 20);

    gather2<0>(featB, idxq, grp8, gA0, gA1);
    gather2<1>(featB, idxq, grp8, gB0, gB1);

    f32x4 acc[8][2];
    #pragma unroll
    for (int t = 0; t < 8; ++t) { acc[t][0] = (f32x4){0.f,0.f,0.f,0.f}; acc[t][1] = (f32x4){0.f,0.f,0.f,0.f}; }

    __syncthreads();                                   // chunk 0 resident

    // ================= GEMM1: 17 chunks (one per kb) =================
#define G1_STEP(SC, SN, WSRC, B0_, B1_, GNEXT)  \
    stage_chunk((WSRC), (SN), tid);             \
    mfma_chunk(acc, (SC), lane, (B0_), (B1_));  \
    GNEXT;                                      \
    __syncthreads();

    G1_STEP(wb0, wb1, w1p +  1*4096, gA0, gA1, (gather2< 2>(featB, idxq, grp8, gA0, gA1)))
    G1_STEP(wb1, wb0, w1p +  2*4096, gB0, gB1, (gather2< 3>(featB, idxq, grp8, gB0, gB1)))
    G1_STEP(wb0, wb1, w1p +  3*4096, gA0, gA1, (gather2< 4>(featB, idxq, grp8, gA0, gA1)))
    G1_STEP(wb1, wb0, w1p +  4*4096, gB0, gB1, (gather2< 5>(featB, idxq, grp8, gB0, gB1)))
    G1_STEP(wb0, wb1, w1p +  5*4096, gA0, gA1, (gather2< 6>(featB, idxq, grp8, gA0, gA1)))
    G1_STEP(wb1, wb0, w1p +  6*4096, gB0, gB1, (gather2< 7>(featB, idxq, grp8, gB0, gB1)))
    G1_STEP(wb0, wb1, w1p +  7*4096, gA0, gA1, (gather2< 8>(featB, idxq, grp8, gA0, gA1)))
    G1_STEP(wb1, wb0, w1p +  8*4096, gB0, gB1, (gather2< 9>(featB, idxq, grp8, gB0, gB1)))
    G1_STEP(wb0, wb1, w1p +  9*4096, gA0, gA1, (gather2<10>(featB, idxq, grp8, gA0, gA1)))
    G1_STEP(wb1, wb0, w1p + 10*4096, gB0, gB1, (gather2<11>(featB, idxq, grp8, gB0, gB1)))
    G1_STEP(wb0, wb1, w1p + 11*4096, gA0, gA1, (gather2<12>(featB, idxq, grp8, gA0, gA1)))
    G1_STEP(wb1, wb0, w1p + 12*4096, gB0, gB1, (gather2<13>(featB, idxq, grp8, gB0, gB1)))
    G1_STEP(wb0, wb1, w1p + 13*4096, gA0, gA1, (gather2<14>(featB, idxq, grp8, gA0, gA1)))
    G1_STEP(wb1, wb0, w1p + 14*4096, gB0, gB1, (gather2<15>(featB, idxq, grp8, gB0, gB1)))
    G1_STEP(wb0, wb1, w1p + 15*4096, gA0, gA1, disload2(disB, p0, l15, grp, gA0, gA1))
    G1_STEP(wb1, wb0, w1p + 16*4096, gB0, gB1, )
#undef G1_STEP
    // kb=16 (dis/zero cols): stage GEMM2 chunk 0, compute, epilogue, barrier
    stage_chunk(w2p, wb1, tid);
    mfma_chunk(acc, wb0, lane, gA0, gA1);
    #pragma unroll
    for (int t = 0; t < 8; ++t) {                      // epilogue 1: bias+relu -> strip (H1)
        const int chb = t * 16 + grp * 4;
        const float4 bv = *(const float4*)(b1 + chb);
        #pragma unroll
        for (int pt = 0; pt < 2; ++pt) {
            s16x4 pk;
            float v0 = acc[t][pt][0] + bv.x; pk[0] = (short)f2bf(v0 > 0.f ? v0 : 0.f);
            float v1 = acc[t][pt][1] + bv.y; pk[1] = (short)f2bf(v1 > 0.f ? v1 : 0.f);
            float v2 = acc[t][pt][2] + bv.z; pk[2] = (short)f2bf(v2 > 0.f ? v2 : 0.f);
            float v3 = acc[t][pt][3] + bv.w; pk[3] = (short)f2bf(v3 > 0.f ? v3 : 0.f);
            *(s16x4*)(strip + (pt * 16 + l15) * 136 + chb) = pk;
        }
    }
    __syncthreads();                                   // GEMM2 chunk 0 resident

    // ================= GEMM2: 4 chunks =================
    f32x4 acc2[8][2];
    #pragma unroll
    for (int t = 0; t < 8; ++t) { acc2[t][0] = (f32x4){0.f,0.f,0.f,0.f}; acc2[t][1] = (f32x4){0.f,0.f,0.f,0.f}; }

    dsread2(strip, 0, l15, grp8, gA0, gA1);

    stage_chunk(w2p + 1*4096, wb0, tid);
    dsread2(strip, 1, l15, grp8, gB0, gB1);
    mfma_chunk(acc2, wb1, lane, gA0, gA1);
    __syncthreads();

    stage_chunk(w2p + 2*4096, wb1, tid);
    dsread2(strip, 2, l15, grp8, gA0, gA1);
    mfma_chunk(acc2, wb0, lane, gB0, gB1);
    __syncthreads();

    stage_chunk(w2p + 3*4096, wb0, tid);
    dsread2(strip, 3, l15, grp8, gB0, gB1);
    mfma_chunk(acc2, wb1, lane, gA0, gA1);
    __syncthreads();

    mfma_chunk(acc2, wb0, lane, gB0, gB1);             // last chunk: no stage, no barrier

    #pragma unroll
    for (int t = 0; t < 8; ++t) {                      // epilogue 2: bias+relu -> strip (H2)
        const int chb = t * 16 + grp * 4;
        const float4 bv = *(const float4*)(b2 + chb);
        #pragma unroll
        for (int pt = 0; pt < 2; ++pt) {
            s16x4 pk;
            float v0 = acc2[t][pt][0] + bv.x; pk[0] = (short)f2bf(v0 > 0.f ? v0 : 0.f);
            float v1 = acc2[t][pt][1] + bv.y; pk[1] = (short)f2bf(v1 > 0.f ? v1 : 0.f);
            float v2 = acc2[t][pt][2] + bv.z; pk[2] = (short)f2bf(v2 > 0.f ? v2 : 0.f);
            float v3 = acc2[t][pt][3] + bv.w; pk[3] = (short)f2bf(v3 > 0.f ? v3 : 0.f);
            *(s16x4*)(strip + (pt * 16 + l15) * 136 + chb) = pk;
        }
    }

    // ================= GEMM3: [256 x 128] * [128 x 32], reg-pipelined, barrier-free =================
    wload4(w3p, 0, lane, wA0, wA1, wA2, wA3);

#define G23_BODY(WP, FR, S0,S1, ACC, WNEXT, DSNEXT)                         \
    wload4(WP, (FR) + 4, lane, wB0, wB1, wB2, wB3);                         \
    mfma_oct(ACC, 0, wA0, wA1, wA2, wA3, S0, S1);                           \
    WNEXT;                                                                  \
    DSNEXT;                                                                 \
    mfma_oct(ACC, 4, wB0, wB1, wB2, wB3, S0, S1);

    #pragma unroll
    for (int half = 0; half < 2; ++half) {
        f32x4 acc3[8][2];
        #pragma unroll
        for (int t = 0; t < 8; ++t) { acc3[t][0] = (f32x4){0.f,0.f,0.f,0.f}; acc3[t][1] = (f32x4){0.f,0.f,0.f,0.f}; }

        dsread2(strip, 0, l15, grp8, gA0, gA1);
        if (half == 0) {
            G23_BODY(w3p,  0, gA0,gA1, acc3, wload4(w3p,  8, lane, wA0,wA1,wA2,wA3), dsread2(strip, 1, l15, grp8, gB0,gB1))
            G23_BODY(w3p,  8, gB0,gB1, acc3, wload4(w3p, 16, lane, wA0,wA1,wA2,wA3), dsread2(strip, 2, l15, grp8, gA0,gA1))
            G23_BODY(w3p, 16, gA0,gA1, acc3, wload4(w3p, 24, lane, wA0,wA1,wA2,wA3), dsread2(strip, 3, l15, grp8, gB0,gB1))
            G23_BODY(w3p, 24, gB0,gB1, acc3, wload4(w3p, 32, lane, wA0,wA1,wA2,wA3), )
        } else {
            G23_BODY(w3p, 32, gA0,gA1, acc3, wload4(w3p, 40, lane, wA0,wA1,wA2,wA3), dsread2(strip, 1, l15, grp8, gB0,gB1))
            G23_BODY(w3p, 40, gB0,gB1, acc3, wload4(w3p, 48, lane, wA0,wA1,wA2,wA3), dsread2(strip, 2, l15, grp8, gA0,gA1))
            G23_BODY(w3p, 48, gA0,gA1, acc3, wload4(w3p, 56, lane, wA0,wA1,wA2,wA3), dsread2(strip, 3, l15, grp8, gB0,gB1))
            G23_BODY(w3p, 56, gB0,gB1, acc3, , )
        }

        #pragma unroll
        for (int t = 0; t < 8; ++t) {
            const int chb = half * 128 + t * 16 + grp * 4;
            const float4 bv = *(const float4*)(b3 + chb);
            #pragma unroll
            for (int pt = 0; pt < 2; ++pt) {
                const int n = n0 + pt * 16 + l15;
                float* op = out + (((size_t)(b * 256 + chb)) << 14) + n;
                op[0]                  = acc3[t][pt][0] + bv.x;
                op[(size_t)1 << 14]    = acc3[t][pt][1] + bv.y;
                op[(size_t)2 << 14]    = acc3[t][pt][2] + bv.z;
                op[(size_t)3 << 14]    = acc3[t][pt][3] + bv.w;
            }
        }
    }
#undef G23_BODY
}

extern "C" void kernel_launch(void* const* d_in, const int* in_sizes, int n_in,
                              void* d_out, int out_size, void* d_ws, size_t ws_size,
                              hipStream_t stream)
{
    const float* feature = (const float*)d_in[0];
    const int*   idx     = (const int*)d_in[1];
    const float* dis     = (const float*)d_in[2];
    const float* W1      = (const float*)d_in[3];
    const float* b1      = (const float*)d_in[4];
    const float* W2      = (const float*)d_in[5];
    const float* b2      = (const float*)d_in[6];
    const float* W3      = (const float*)d_in[7];
    const float* b3      = (const float*)d_in[8];
    float* out = (float*)d_out;

    char* ws = (char*)d_ws;
    unsigned short* featT = (unsigned short*)ws;
    unsigned short* disB  = (unsigned short*)(ws + OFF_DISB);
    unsigned short* w1p   = (unsigned short*)(ws + OFF_W1B);
    unsigned short* w2p   = (unsigned short*)(ws + OFF_W2B);
    unsigned short* w3p   = (unsigned short*)(ws + OFF_W3B);

    hipLaunchKernelGGL(prep_misc, dim3(570), dim3(256), 0, stream,
                       dis, W1, W2, W3, disB, w1p, w2p, w3p);
    hipLaunchKernelGGL(prep_featT, dim3(512), dim3(256), 0, stream, feature, featT);
    hipLaunchKernelGGL(pointconv_main, dim3(1024), dim3(256), 0, stream,
                       featT, disB, idx, w1p, w2p, w3p, b1, b2, b3, out);
}

// Round 9
// 74.646 us; speedup vs baseline: 1.2680x; 1.1689x over previous
//
#include <hip/hip_runtime.h>
#include <hip/hip_bf16.h>
#include <stdint.h>

// Problem constants
#define BB 8
#define CC 64
#define NN 16384
#define KNB 8            // neighbors
// Padded GEMM1 K (REPERMUTED): cols kk*64+c = feature[c][idx[kk]] for kk=0..7,
// cols 512..519 = dis[0..7], cols 520..543 = 0.  (17 kb-steps of 32)

typedef __attribute__((ext_vector_type(8))) short   s16x8;
typedef __attribute__((ext_vector_type(4))) short   s16x4;
typedef __attribute__((ext_vector_type(8))) __bf16  bf16x8;
typedef __attribute__((ext_vector_type(4))) float   f32x4;

__device__ __forceinline__ unsigned short f2bf(float f) {
    unsigned u = __builtin_bit_cast(unsigned, f);
    u = (u + 0x7FFFu + ((u >> 16) & 1u)) >> 16;   // RNE, inputs finite
    return (unsigned short)u;
}

__device__ __forceinline__ int getq(const int4& q, int j) {
    return j == 0 ? q.x : j == 1 ? q.y : j == 2 ? q.z : q.w;   // j constant-folds after unroll
}

// ---- workspace layout (bytes) ----
#define OFF_DISB  16777216u
#define OFF_W1B   18874368u
#define OFF_W2B   19013632u
#define OFF_W3B   19046400u

// ---------------- merged prep: featT transpose + dis->bf16 + weights frag-major ----------------
// blocks 0..511   : featT  (feature [B][C][N] fp32 -> featT [B][N][C] bf16), 131072 threads
// blocks 512..1487: misc   (disB 131072 thr; W1p 8704; W2p 2048; W3p 4096 = 249856 thr = 976 blocks)
__global__ __launch_bounds__(256) void prep_all(
    const float* __restrict__ feat, const float* __restrict__ dis,
    const float* __restrict__ W1, const float* __restrict__ W2, const float* __restrict__ W3,
    unsigned short* __restrict__ featT, unsigned short* __restrict__ disB,
    unsigned short* __restrict__ w1p, unsigned short* __restrict__ w2p,
    unsigned short* __restrict__ w3p)
{
    const int bid = blockIdx.x;
    if (bid < 512) {
        int gt = bid * 256 + threadIdx.x;          // global point 0..131071
        int b = gt >> 14, n = gt & 16383;
        const float* fp = feat + ((size_t)b << 20) + n;
        unsigned short v[64];
        #pragma unroll
        for (int c = 0; c < 64; ++c) v[c] = f2bf(fp[(size_t)c << 14]);  // coalesced across lanes
        unsigned short* dst = featT + (size_t)gt * 64;
        #pragma unroll
        for (int j = 0; j < 8; ++j) {
            s16x8 pk;
            #pragma unroll
            for (int i = 0; i < 8; ++i) pk[i] = (short)v[j * 8 + i];
            *(s16x8*)(dst + j * 8) = pk;
        }
        return;
    }
    int tid = (bid - 512) * 256 + threadIdx.x;
    if (tid < 131072) {                        // one POINT per thread: 8 dis values
        const float* dp = dis + (size_t)tid * 8;
        s16x8 pk;
        #pragma unroll
        for (int j = 0; j < 8; ++j) pk[j] = (short)f2bf(dp[j]);
        *(s16x8*)(disB + (size_t)tid * 8) = pk;
        return;
    }
    int t2 = tid - 131072;
    if (t2 < 8704) {                           // W1p: kb 0..16, t 0..7, lane 0..63
        int kb   = t2 >> 9;
        int rem  = t2 & 511;
        int t    = rem >> 6;
        int lane = rem & 63;
        int row  = t * 16 + (lane & 15);
        int kbase = kb * 32 + (lane >> 4) * 8;
        s16x8 pk;
        #pragma unroll
        for (int j = 0; j < 8; ++j) {
            int kp = kbase + j;
            float val = 0.f;
            if (kp < 512) {                                          // feature weights
                int kk = kp >> 6, c = kp & 63;
                val = W1[row * 520 + kk * 65 + 1 + c];
            } else if (kp < 520) {                                   // dis weight of neighbor kp-512
                val = W1[row * 520 + (kp - 512) * 65];
            }
            pk[j] = (short)f2bf(val);
        }
        *(s16x8*)(w1p + (size_t)t2 * 8) = pk;
    } else if (t2 < 8704 + 2048) {             // W2p
        int f    = t2 - 8704;
        int kb   = f >> 9;
        int rem  = f & 511;
        int t    = rem >> 6;
        int lane = rem & 63;
        int row  = t * 16 + (lane & 15);
        int k    = kb * 32 + (lane >> 4) * 8;
        s16x8 pk;
        #pragma unroll
        for (int j = 0; j < 8; ++j) pk[j] = (short)f2bf(W2[row * 128 + k + j]);
        *(s16x8*)(w2p + (size_t)f * 8) = pk;
    } else if (t2 < 8704 + 2048 + 4096) {      // W3p
        int f    = t2 - 10752;
        int hk   = f >> 9;
        int half = hk >> 2, kb = hk & 3;
        int rem  = f & 511;
        int t    = rem >> 6;
        int lane = rem & 63;
        int row  = (half * 8 + t) * 16 + (lane & 15);
        int k    = kb * 32 + (lane >> 4) * 8;
        s16x8 pk;
        #pragma unroll
        for (int j = 0; j < 8; ++j) pk[j] = (short)f2bf(W3[row * 128 + k + j]);
        *(s16x8*)(w3p + (size_t)f * 8) = pk;
    }
}

// ---------------- main fused kernel helpers ----------------
__device__ __forceinline__ void wload4(const unsigned short* wp, int frag0, int lane,
                                       bf16x8& w0, bf16x8& w1, bf16x8& w2, bf16x8& w3)
{
    w0 = *(const bf16x8*)(wp + (size_t)((frag0 + 0) * 64 + lane) * 8);
    w1 = *(const bf16x8*)(wp + (size_t)((frag0 + 1) * 64 + lane) * 8);
    w2 = *(const bf16x8*)(wp + (size_t)((frag0 + 2) * 64 + lane) * 8);
    w3 = *(const bf16x8*)(wp + (size_t)((frag0 + 3) * 64 + lane) * 8);
}

// iq[] holds the CURRENT half of each point's idx row (kk&3 indexes within it);
// the half is swapped by refresh_iq at the kb 7->8 boundary. Saves 16 VGPRs vs [4][2].
template <int KB>
__device__ __forceinline__ void gather4(const unsigned short* featB, const int4 (&iq)[4],
                                        int grp8, bf16x8& G0, bf16x8& G1, bf16x8& G2, bf16x8& G3)
{
    constexpr int kk = KB >> 1;
    constexpr int j  = kk & 3;
    const int c0 = (KB & 1) * 32 + grp8;
    G0 = *(const bf16x8*)(featB + (((size_t)(unsigned)getq(iq[0], j)) << 6) + c0);
    G1 = *(const bf16x8*)(featB + (((size_t)(unsigned)getq(iq[1], j)) << 6) + c0);
    G2 = *(const bf16x8*)(featB + (((size_t)(unsigned)getq(iq[2], j)) << 6) + c0);
    G3 = *(const bf16x8*)(featB + (((size_t)(unsigned)getq(iq[3], j)) << 6) + c0);
}

__device__ __forceinline__ void refresh_iq(int4 (&iq)[4], const int* ip0) {
    #pragma unroll
    for (int pt = 0; pt < 4; ++pt) iq[pt] = *(const int4*)(ip0 + pt * 128 + 4);   // hi half (kk 4..7)
}

// dis columns (kb=16 data): grp 0 lanes carry dis[0..7], other grps are zero pad
__device__ __forceinline__ void disload4(const unsigned short* disB, int p0, int l15, int grp,
                                         bf16x8& G0, bf16x8& G1, bf16x8& G2, bf16x8& G3)
{
    const s16x8 z = {0,0,0,0,0,0,0,0};
    if (grp == 0) {
        G0 = *(const bf16x8*)(disB + (size_t)(p0 +  0 + l15) * 8);
        G1 = *(const bf16x8*)(disB + (size_t)(p0 + 16 + l15) * 8);
        G2 = *(const bf16x8*)(disB + (size_t)(p0 + 32 + l15) * 8);
        G3 = *(const bf16x8*)(disB + (size_t)(p0 + 48 + l15) * 8);
    } else {
        G0 = __builtin_bit_cast(bf16x8, z); G1 = __builtin_bit_cast(bf16x8, z);
        G2 = __builtin_bit_cast(bf16x8, z); G3 = __builtin_bit_cast(bf16x8, z);
    }
}

__device__ __forceinline__ void dsread4(const unsigned short* strip, int kb, int l15, int grp8,
                                        bf16x8& G0, bf16x8& G1, bf16x8& G2, bf16x8& G3)
{
    G0 = *(const bf16x8*)(strip + (0 * 16 + l15) * 136 + kb * 32 + grp8);
    G1 = *(const bf16x8*)(strip + (1 * 16 + l15) * 136 + kb * 32 + grp8);
    G2 = *(const bf16x8*)(strip + (2 * 16 + l15) * 136 + kb * 32 + grp8);
    G3 = *(const bf16x8*)(strip + (3 * 16 + l15) * 136 + kb * 32 + grp8);
}

__device__ __forceinline__ void mfma_quad(f32x4 (&ac)[8][4], int t0,
    const bf16x8& wa, const bf16x8& wb, const bf16x8& wc, const bf16x8& wd,
    const bf16x8& B0, const bf16x8& B1, const bf16x8& B2, const bf16x8& B3)
{
    ac[t0+0][0] = __builtin_amdgcn_mfma_f32_16x16x32_bf16(wa, B0, ac[t0+0][0], 0, 0, 0);
    ac[t0+0][1] = __builtin_amdgcn_mfma_f32_16x16x32_bf16(wa, B1, ac[t0+0][1], 0, 0, 0);
    ac[t0+0][2] = __builtin_amdgcn_mfma_f32_16x16x32_bf16(wa, B2, ac[t0+0][2], 0, 0, 0);
    ac[t0+0][3] = __builtin_amdgcn_mfma_f32_16x16x32_bf16(wa, B3, ac[t0+0][3], 0, 0, 0);
    ac[t0+1][0] = __builtin_amdgcn_mfma_f32_16x16x32_bf16(wb, B0, ac[t0+1][0], 0, 0, 0);
    ac[t0+1][1] = __builtin_amdgcn_mfma_f32_16x16x32_bf16(wb, B1, ac[t0+1][1], 0, 0, 0);
    ac[t0+1][2] = __builtin_amdgcn_mfma_f32_16x16x32_bf16(wb, B2, ac[t0+1][2], 0, 0, 0);
    ac[t0+1][3] = __builtin_amdgcn_mfma_f32_16x16x32_bf16(wb, B3, ac[t0+1][3], 0, 0, 0);
    ac[t0+2][0] = __builtin_amdgcn_mfma_f32_16x16x32_bf16(wc, B0, ac[t0+2][0], 0, 0, 0);
    ac[t0+2][1] = __builtin_amdgcn_mfma_f32_16x16x32_bf16(wc, B1, ac[t0+2][1], 0, 0, 0);
    ac[t0+2][2] = __builtin_amdgcn_mfma_f32_16x16x32_bf16(wc, B2, ac[t0+2][2], 0, 0, 0);
    ac[t0+2][3] = __builtin_amdgcn_mfma_f32_16x16x32_bf16(wc, B3, ac[t0+2][3], 0, 0, 0);
    ac[t0+3][0] = __builtin_amdgcn_mfma_f32_16x16x32_bf16(wd, B0, ac[t0+3][0], 0, 0, 0);
    ac[t0+3][1] = __builtin_amdgcn_mfma_f32_16x16x32_bf16(wd, B1, ac[t0+3][1], 0, 0, 0);
    ac[t0+3][2] = __builtin_amdgcn_mfma_f32_16x16x32_bf16(wd, B2, ac[t0+3][2], 0, 0, 0);
    ac[t0+3][3] = __builtin_amdgcn_mfma_f32_16x16x32_bf16(wd, B3, ac[t0+3][3], 0, 0, 0);
}

// ---------------- main fused kernel ----------------
// 1 wave per block, 64 points per wave (R6 structure, best known). Software-pipelined:
// gathers 2-deep reg dbuf, weights quad-dbuf threaded through all three GEMMs, zero barriers.
// __launch_bounds__(64,2): force unified VGPR+AGPR <= 256 so 2 waves/SIMD are resident
// (R6 likely ran at 1 wave/SIMD: ~144 VGPR + 128 AGPR > 256 unified budget).
__global__ __launch_bounds__(64, 2) void pointconv_main(
    const unsigned short* __restrict__ featT,
    const unsigned short* __restrict__ disB,
    const int* __restrict__ idx,
    const unsigned short* __restrict__ w1p,
    const unsigned short* __restrict__ w2p,
    const unsigned short* __restrict__ w3p,
    const float* __restrict__ b1, const float* __restrict__ b2,
    const float* __restrict__ b3, float* __restrict__ out)
{
    __shared__ __align__(16) unsigned short strip[64 * 136];   // 17,408 B
    const int bid  = blockIdx.x;
    const int wg   = (bid & 7) * 256 + (bid >> 3);     // XCD-aware bijective swizzle
    const int lane = threadIdx.x;                      // 0..63
    const int grp  = lane >> 4;
    const int grp8 = grp * 8;
    const int l15  = lane & 15;
    const int p0   = wg * 64;
    const int b    = p0 >> 14;
    const int n0   = p0 & 16383;

    // pipeline registers
    bf16x8 gA0, gA1, gA2, gA3, gB0, gB1, gB2, gB3;     // B-frag double buffer
    bf16x8 wA0, wA1, wA2, wA3, wB0, wB1, wB2, wB3;     // weight quad double buffer

    // ---- prolog: first weights, idx lo-half, first two gather sets ----
    wload4(w1p, 0, lane, wA0, wA1, wA2, wA3);          // Q(0,0)

    const int* ip0 = idx + (size_t)(p0 + l15) * 8;
    int4 iq[4];
    #pragma unroll
    for (int pt = 0; pt < 4; ++pt) iq[pt] = *(const int4*)(ip0 + pt * 128);   // kk 0..3

    const unsigned short* featB = featT + ((size_t)b << 20);

    gather4<0>(featB, iq, grp8, gA0, gA1, gA2, gA3);
    gather4<1>(featB, iq, grp8, gB0, gB1, gB2, gB3);

    // ================= GEMM1: [128 x 544] * [544 x 64] =================
    f32x4 acc[8][4];
    #pragma unroll
    for (int t = 0; t < 8; ++t)
        #pragma unroll
        for (int pt = 0; pt < 4; ++pt) acc[t][pt] = (f32x4){0.f, 0.f, 0.f, 0.f};

#define G1_BODY(KB, S0,S1,S2,S3, WNEXT, GNEXT)                              \
    wload4(w1p, (KB)*8 + 4, lane, wB0, wB1, wB2, wB3);                      \
    mfma_quad(acc, 0, wA0, wA1, wA2, wA3, S0, S1, S2, S3);                  \
    WNEXT;                                                                  \
    mfma_quad(acc, 4, wB0, wB1, wB2, wB3, S0, S1, S2, S3);                  \
    GNEXT;

    G1_BODY(0,  gA0,gA1,gA2,gA3, wload4(w1p,  8, lane, wA0,wA1,wA2,wA3), (gather4< 2>(featB, iq, grp8, gA0,gA1,gA2,gA3)))
    G1_BODY(1,  gB0,gB1,gB2,gB3, wload4(w1p, 16, lane, wA0,wA1,wA2,wA3), (gather4< 3>(featB, iq, grp8, gB0,gB1,gB2,gB3)))
    G1_BODY(2,  gA0,gA1,gA2,gA3, wload4(w1p, 24, lane, wA0,wA1,wA2,wA3), (gather4< 4>(featB, iq, grp8, gA0,gA1,gA2,gA3)))
    G1_BODY(3,  gB0,gB1,gB2,gB3, wload4(w1p, 32, lane, wA0,wA1,wA2,wA3), (gather4< 5>(featB, iq, grp8, gB0,gB1,gB2,gB3)))
    G1_BODY(4,  gA0,gA1,gA2,gA3, wload4(w1p, 40, lane, wA0,wA1,wA2,wA3), (gather4< 6>(featB, iq, grp8, gA0,gA1,gA2,gA3)))
    G1_BODY(5,  gB0,gB1,gB2,gB3, wload4(w1p, 48, lane, wA0,wA1,wA2,wA3), (gather4< 7>(featB, iq, grp8, gB0,gB1,gB2,gB3)))
    refresh_iq(iq, ip0);                                // swap to hi half (kk 4..7); lo last used by gather<7>
    G1_BODY(6,  gA0,gA1,gA2,gA3, wload4(w1p, 56, lane, wA0,wA1,wA2,wA3), (gather4< 8>(featB, iq, grp8, gA0,gA1,gA2,gA3)))
    G1_BODY(7,  gB0,gB1,gB2,gB3, wload4(w1p, 64, lane, wA0,wA1,wA2,wA3), (gather4< 9>(featB, iq, grp8, gB0,gB1,gB2,gB3)))
    G1_BODY(8,  gA0,gA1,gA2,gA3, wload4(w1p, 72, lane, wA0,wA1,wA2,wA3), (gather4<10>(featB, iq, grp8, gA0,gA1,gA2,gA3)))
    G1_BODY(9,  gB0,gB1,gB2,gB3, wload4(w1p, 80, lane, wA0,wA1,wA2,wA3), (gather4<11>(featB, iq, grp8, gB0,gB1,gB2,gB3)))
    G1_BODY(10, gA0,gA1,gA2,gA3, wload4(w1p, 88, lane, wA0,wA1,wA2,wA3), (gather4<12>(featB, iq, grp8, gA0,gA1,gA2,gA3)))
    G1_BODY(11, gB0,gB1,gB2,gB3, wload4(w1p, 96, lane, wA0,wA1,wA2,wA3), (gather4<13>(featB, iq, grp8, gB0,gB1,gB2,gB3)))
    G1_BODY(12, gA0,gA1,gA2,gA3, wload4(w1p,104, lane, wA0,wA1,wA2,wA3), (gather4<14>(featB, iq, grp8, gA0,gA1,gA2,gA3)))
    G1_BODY(13, gB0,gB1,gB2,gB3, wload4(w1p,112, lane, wA0,wA1,wA2,wA3), (gather4<15>(featB, iq, grp8, gB0,gB1,gB2,gB3)))
    // kb=14: "next gather" slot loads the dis columns (kb=16 data) into the gA set
    G1_BODY(14, gA0,gA1,gA2,gA3, wload4(w1p,120, lane, wA0,wA1,wA2,wA3), disload4(disB, p0, l15, grp, gA0,gA1,gA2,gA3))
    G1_BODY(15, gB0,gB1,gB2,gB3, wload4(w1p,128, lane, wA0,wA1,wA2,wA3), )
    // kb=16 (dis/zero cols); next-weight prefetch chains into GEMM2's first quad
    G1_BODY(16, gA0,gA1,gA2,gA3, wload4(w2p, 0, lane, wA0,wA1,wA2,wA3), )
#undef G1_BODY

    // epilogue 1: bias + relu -> strip[pt][ch] bf16
    #pragma unroll
    for (int t = 0; t < 8; ++t) {
        const int chb = t * 16 + grp * 4;
        const float4 bv = *(const float4*)(b1 + chb);
        #pragma unroll
        for (int pt = 0; pt < 4; ++pt) {
            s16x4 pk;
            float v0 = acc[t][pt][0] + bv.x; pk[0] = (short)f2bf(v0 > 0.f ? v0 : 0.f);
            float v1 = acc[t][pt][1] + bv.y; pk[1] = (short)f2bf(v1 > 0.f ? v1 : 0.f);
            float v2 = acc[t][pt][2] + bv.z; pk[2] = (short)f2bf(v2 > 0.f ? v2 : 0.f);
            float v3 = acc[t][pt][3] + bv.w; pk[3] = (short)f2bf(v3 > 0.f ? v3 : 0.f);
            *(s16x4*)(strip + (pt * 16 + l15) * 136 + chb) = pk;
        }
    }

    // ================= GEMM2: [128 x 128] * [128 x 64] =================
    f32x4 acc2[8][4];
    #pragma unroll
    for (int t = 0; t < 8; ++t)
        #pragma unroll
        for (int pt = 0; pt < 4; ++pt) acc2[t][pt] = (f32x4){0.f, 0.f, 0.f, 0.f};

    dsread4(strip, 0, l15, grp8, gA0, gA1, gA2, gA3);

#define G23_BODY(WP, FR, S0,S1,S2,S3, ACC, WNEXT, DSNEXT)                   \
    wload4(WP, (FR) + 4, lane, wB0, wB1, wB2, wB3);                         \
    mfma_quad(ACC, 0, wA0, wA1, wA2, wA3, S0, S1, S2, S3);                  \
    WNEXT;                                                                  \
    DSNEXT;                                                                 \
    mfma_quad(ACC, 4, wB0, wB1, wB2, wB3, S0, S1, S2, S3);

    G23_BODY(w2p,  0, gA0,gA1,gA2,gA3, acc2, wload4(w2p,  8, lane, wA0,wA1,wA2,wA3), dsread4(strip, 1, l15, grp8, gB0,gB1,gB2,gB3))
    G23_BODY(w2p,  8, gB0,gB1,gB2,gB3, acc2, wload4(w2p, 16, lane, wA0,wA1,wA2,wA3), dsread4(strip, 2, l15, grp8, gA0,gA1,gA2,gA3))
    G23_BODY(w2p, 16, gA0,gA1,gA2,gA3, acc2, wload4(w2p, 24, lane, wA0,wA1,wA2,wA3), dsread4(strip, 3, l15, grp8, gB0,gB1,gB2,gB3))
    G23_BODY(w2p, 24, gB0,gB1,gB2,gB3, acc2, wload4(w3p,  0, lane, wA0,wA1,wA2,wA3), )

    // epilogue 2: bias + relu -> strip (H1 fully consumed; same-wave ordering)
    #pragma unroll
    for (int t = 0; t < 8; ++t) {
        const int chb = t * 16 + grp * 4;
        const float4 bv = *(const float4*)(b2 + chb);
        #pragma unroll
        for (int pt = 0; pt < 4; ++pt) {
            s16x4 pk;
            float v0 = acc2[t][pt][0] + bv.x; pk[0] = (short)f2bf(v0 > 0.f ? v0 : 0.f);
            float v1 = acc2[t][pt][1] + bv.y; pk[1] = (short)f2bf(v1 > 0.f ? v1 : 0.f);
            float v2 = acc2[t][pt][2] + bv.z; pk[2] = (short)f2bf(v2 > 0.f ? v2 : 0.f);
            float v3 = acc2[t][pt][3] + bv.w; pk[3] = (short)f2bf(v3 > 0.f ? v3 : 0.f);
            *(s16x4*)(strip + (pt * 16 + l15) * 136 + chb) = pk;
        }
    }

    // ================= GEMM3: [256 x 128] * [128 x 64], two halves =================
    #pragma unroll
    for (int half = 0; half < 2; ++half) {
        f32x4 acc3[8][4];
        #pragma unroll
        for (int t = 0; t < 8; ++t)
            #pragma unroll
            for (int pt = 0; pt < 4; ++pt) acc3[t][pt] = (f32x4){0.f, 0.f, 0.f, 0.f};

        dsread4(strip, 0, l15, grp8, gA0, gA1, gA2, gA3);
        if (half == 0) {
            G23_BODY(w3p,  0, gA0,gA1,gA2,gA3, acc3, wload4(w3p,  8, lane, wA0,wA1,wA2,wA3), dsread4(strip, 1, l15, grp8, gB0,gB1,gB2,gB3))
            G23_BODY(w3p,  8, gB0,gB1,gB2,gB3, acc3, wload4(w3p, 16, lane, wA0,wA1,wA2,wA3), dsread4(strip, 2, l15, grp8, gA0,gA1,gA2,gA3))
            G23_BODY(w3p, 16, gA0,gA1,gA2,gA3, acc3, wload4(w3p, 24, lane, wA0,wA1,wA2,wA3), dsread4(strip, 3, l15, grp8, gB0,gB1,gB2,gB3))
            G23_BODY(w3p, 24, gB0,gB1,gB2,gB3, acc3, wload4(w3p, 32, lane, wA0,wA1,wA2,wA3), )
        } else {
            G23_BODY(w3p, 32, gA0,gA1,gA2,gA3, acc3, wload4(w3p, 40, lane, wA0,wA1,wA2,wA3), dsread4(strip, 1, l15, grp8, gB0,gB1,gB2,gB3))
            G23_BODY(w3p, 40, gB0,gB1,gB2,gB3, acc3, wload4(w3p, 48, lane, wA0,wA1,wA2,wA3), dsread4(strip, 2, l15, grp8, gA0,gA1,gA2,gA3))
            G23_BODY(w3p, 48, gA0,gA1,gA2,gA3, acc3, wload4(w3p, 56, lane, wA0,wA1,wA2,wA3), dsread4(strip, 3, l15, grp8, gB0,gB1,gB2,gB3))
            G23_BODY(w3p, 56, gB0,gB1,gB2,gB3, acc3, , )
        }

        #pragma unroll
        for (int t = 0; t < 8; ++t) {
            const int chb = half * 128 + t * 16 + grp * 4;
            const float4 bv = *(const float4*)(b3 + chb);
            #pragma unroll
            for (int pt = 0; pt < 4; ++pt) {
                const int n = n0 + pt * 16 + l15;
                float* op = out + (((size_t)(b * 256 + chb)) << 14) + n;
                op[0]                  = acc3[t][pt][0] + bv.x;
                op[(size_t)1 << 14]    = acc3[t][pt][1] + bv.y;
                op[(size_t)2 << 14]    = acc3[t][pt][2] + bv.z;
                op[(size_t)3 << 14]    = acc3[t][pt][3] + bv.w;
            }
        }
    }
#undef G23_BODY
}

extern "C" void kernel_launch(void* const* d_in, const int* in_sizes, int n_in,
                              void* d_out, int out_size, void* d_ws, size_t ws_size,
                              hipStream_t stream)
{
    const float* feature = (const float*)d_in[0];
    const int*   idx     = (const int*)d_in[1];
    const float* dis     = (const float*)d_in[2];
    const float* W1      = (const float*)d_in[3];
    const float* b1      = (const float*)d_in[4];
    const float* W2      = (const float*)d_in[5];
    const float* b2      = (const float*)d_in[6];
    const float* W3      = (const float*)d_in[7];
    const float* b3      = (const float*)d_in[8];
    float* out = (float*)d_out;

    char* ws = (char*)d_ws;
    unsigned short* featT = (unsigned short*)ws;
    unsigned short* disB  = (unsigned short*)(ws + OFF_DISB);
    unsigned short* w1p   = (unsigned short*)(ws + OFF_W1B);
    unsigned short* w2p   = (unsigned short*)(ws + OFF_W2B);
    unsigned short* w3p   = (unsigned short*)(ws + OFF_W3B);

    hipLaunchKernelGGL(prep_all, dim3(1488), dim3(256), 0, stream,
                       feature, dis, W1, W2, W3, featT, disB, w1p, w2p, w3p);
    hipLaunchKernelGGL(pointconv_main, dim3(2048), dim3(64), 0, stream,
                       featT, disB, idx, w1p, w2p, w3p, b1, b2, b3, out);
}